// Round 2
// baseline (304.482 us; speedup 1.0000x reference)
//
#include <hip/hip_runtime.h>
#include <stdint.h>

// Problem constants (fixed by reference setup_inputs)
#define B_ROWS 4096
#define D_DIM  512
#define K_CODES 16384
#define EPS 1e-6f

typedef __attribute__((ext_vector_type(8))) short short8;   // 8 bf16 (raw bits)
typedef __attribute__((ext_vector_type(4))) float floatx4;  // MFMA accumulator

__device__ __forceinline__ unsigned short f2bf(float f) {
  // round-to-nearest-even fp32 -> bf16 (inputs finite, no NaN handling)
  unsigned int u = __float_as_uint(f);
  u += 0x7FFFu + ((u >> 16) & 1u);
  return (unsigned short)(u >> 16);
}
__device__ __forceinline__ float bf2f(unsigned short h) {
  return __uint_as_float(((unsigned int)h) << 16);
}

__device__ __forceinline__ void load_lds16(const short* g, short* l) {
  // async global->LDS, 16B/lane; LDS dest = wave-uniform base + lane*16
  __builtin_amdgcn_global_load_lds(
      (const __attribute__((address_space(1))) void*)g,
      (__attribute__((address_space(3))) void*)l, 16, 0, 0);
}

// ---------------------------------------------------------------------------
// prep (single launch; unchanged):
//  blocks 0..2047  : w-tile path. w (512x16384 f32) -> W_cat (16384x1024 bf16
//                    [w_hi|w_lo], K-major) via 64x64 LDS transpose (+1 pad),
//                    float4 reads, short8 (16B) stores. Also writes per-chunk
//                    colpart[c][k] = sum_d(w^2) - 2*eps*sum_d(w) (8 d-chunks;
//                    summed by the gemm epilogue -- no atomics, deterministic).
//  blocks 2048..2303: x path. x (4096x512) -> A_cat (4096x1024 [x_hi|x_lo]) +
//                    row_term[b] = sum(x^2)+2*eps*sum(x)+D*eps^2. One wave per
//                    row, 16 rows/block. Block 2048 inits loss/counter.
// ---------------------------------------------------------------------------
__global__ void prep_kernel(const float* __restrict__ x,
                            const float* __restrict__ w,
                            short* __restrict__ A, short* __restrict__ W,
                            float* __restrict__ row_term,
                            float* __restrict__ colpart,
                            float* __restrict__ loss_acc,
                            unsigned int* __restrict__ counter) {
  const int bid = blockIdx.x;
  const int t = threadIdx.x;  // 256
  if (bid < 2048) {
    __shared__ float tile[64][65];
    const int k0 = (bid & 255) * 64;
    const int dchunk = bid >> 8;  // 0..7
    const int d0 = dchunk * 64;
#pragma unroll
    for (int i = 0; i < 4; ++i) {
      int idx = i * 256 + t;
      int r = idx >> 4, c4 = (idx & 15) * 4;  // r: d-local
      float4 v = *(const float4*)&w[(size_t)(d0 + r) * K_CODES + k0 + c4];
      tile[r][c4 + 0] = v.x;
      tile[r][c4 + 1] = v.y;
      tile[r][c4 + 2] = v.z;
      tile[r][c4 + 3] = v.w;
    }
    __syncthreads();
    const int sub = t & 7;    // d-subgroup within a k row
    const int cd8 = sub * 8;  // 8 consecutive d
#pragma unroll
    for (int g = 0; g < 2; ++g) {
      const int rk = (t >> 3) + g * 32;  // k-local 0..63
      short8 hi, lo;
      float s = 0.f, q = 0.f;
#pragma unroll
      for (int j = 0; j < 8; ++j) {
        float v = tile[cd8 + j][rk];
        s += v;
        q += v * v;
        unsigned short h = f2bf(v);
        float r2 = v - bf2f(h);
        hi[j] = (short)h;
        lo[j] = (short)f2bf(r2);
      }
      *(short8*)(W + (size_t)(k0 + rk) * 1024 + d0 + cd8) = hi;
      *(short8*)(W + (size_t)(k0 + rk) * 1024 + 512 + d0 + cd8) = lo;
#pragma unroll
      for (int m = 1; m < 8; m <<= 1) {
        s += __shfl_xor(s, m, 64);
        q += __shfl_xor(q, m, 64);
      }
      if (sub == 0)
        colpart[(size_t)dchunk * K_CODES + k0 + rk] = q - 2.0f * EPS * s;
    }
  } else {
    const int xb = bid - 2048;  // 0..255
    if (xb == 0 && t == 0) { loss_acc[0] = 0.0f; counter[0] = 0u; }
    const int wv = t >> 6, lane = t & 63;
#pragma unroll
    for (int i = 0; i < 4; ++i) {
      const int b = xb * 16 + i * 4 + wv;  // one wave per row
      const float* xr = x + (size_t)b * D_DIM;
      float4 v0 = ((const float4*)xr)[lane * 2];
      float4 v1 = ((const float4*)xr)[lane * 2 + 1];
      float vals[8] = {v0.x, v0.y, v0.z, v0.w, v1.x, v1.y, v1.z, v1.w};
      short8 hi, lo;
      float s = 0.f, q = 0.f;
#pragma unroll
      for (int j = 0; j < 8; ++j) {
        float v = vals[j];
        s += v;
        q += v * v;
        unsigned short h = f2bf(v);
        float r = v - bf2f(h);
        hi[j] = (short)h;
        lo[j] = (short)f2bf(r);
      }
      *(short8*)(A + (size_t)b * 1024 + lane * 8) = hi;
      *(short8*)(A + (size_t)b * 1024 + 512 + lane * 8) = lo;
#pragma unroll
      for (int m = 1; m < 64; m <<= 1) {
        s += __shfl_xor(s, m, 64);
        q += __shfl_xor(q, m, 64);
      }
      if (lane == 0) row_term[b] = q + 2.0f * EPS * s + (float)D_DIM * EPS * EPS;
    }
  }
}

// ---------------------------------------------------------------------------
// som_gemm (R6): 256x256 tile, BK=64, 512 threads = 8 waves (2M x 4N),
// per-wave 128x64 output = acc[8][4]. 4-phase pipeline per K-tile; R6 change:
// COUNTED vmcnt with 2-tile prefetch depth (T4) instead of R5's per-tile
// vmcnt(0) drain (m218: counted vs drain0 = +38..73%; drain0 ~== unpipelined).
//   prologue: stage(0)->buf0, stage(1)->buf1, vmcnt(8) [tile0 landed,
//             tile1 in flight], barrier.
//   P0(t): ds_read af[0-3]+bf[0-1] (12xb128); bar; lgkm0; prio1; 16 MFMA; bar
//   P1(t): ds_read bf[2-3] (4); bar; lgkm0; prio1; 16 MFMA; bar
//   P2(t): ds_read af[4-7] (8, reuse regs); bar; lgkm0; prio1; 16 MFMA; bar
//          [last reads of buf c -> after P2's barrier buf c is free]
//   P3(t): issue stage(t+2)->buf c (8 loads); 16 MFMA; sched_barrier;
//          vmcnt(8) [retires tile t+1's 8 loads -- 4 full phases of cover --
//          leaves t+2's 8 in flight; NEVER drains to 0 mid-loop]; bar.
//          Tail (t>=22): vmcnt(0) (nothing younger in flight; drain is free).
// Per-wave vmcnt + following s_barrier makes completion a global guarantee
// (each wave certifies its own staged chunks before the barrier).
// Raw s_barrier throughout (no implicit vmcnt(0) drain of __syncthreads).
// XOR-swizzled LDS identical to R2 scheme. MFMA accumulation order per acc
// element identical (kt asc, ks asc) -> bitwise-identical d2.
// XCD swizzle (bijective, 1024%8==0): each XCD owns an 8-nt panel = 4MB of
// W_cat = one L2; 16 mt-blocks re-hit it (R5 verified: FETCH 198->115MB).
// ---------------------------------------------------------------------------
__global__ __launch_bounds__(512, 2) void som_gemm_kernel(
    const short* __restrict__ A, const short* __restrict__ W,
    const float* __restrict__ row_term, const float* __restrict__ colpart,
    unsigned long long* __restrict__ partial) {
  __shared__ __align__(16) short As[2 * 16384];  // 2 x 256x64 bf16 = 64 KB
  __shared__ __align__(16) short Bs[2 * 16384];  // 64 KB

  const int bid = blockIdx.x;           // 0..1023
  const int xcd = bid & 7, lid = bid >> 3;
  const int mt = lid >> 3;              // 0..15
  const int nt = xcd * 8 + (lid & 7);   // 0..63 (bijective XCD grouping)
  const int m0 = mt * 256, n0 = nt * 256;

  const int tid = threadIdx.x;          // 512
  const int wv = tid >> 6, lane = tid & 63;
  const int wm = wv >> 2, wn = wv & 3;  // wave -> 128x64 output sub-tile
  const int q = lane >> 4, l15 = lane & 15;

  // staging address pieces (pre-swizzled global source, linear LDS dest)
  const int srow = lane >> 3;
  const int scol = ((lane & 7) ^ (srow & 7)) * 8;

  // fragment-read address pieces (row&7 == l15&7 since offsets are mult of 8)
  const int arow = (wm * 128 + l15) * 64;  // + mi*1024
  const int brow = (wn * 64 + l15) * 64;   // + ni*1024
  const int col0 = ((0 + q) ^ (l15 & 7)) * 8;  // ks=0 swizzled col
  const int col1 = ((4 + q) ^ (l15 & 7)) * 8;  // ks=1 swizzled col

  floatx4 acc[8][4];
  const floatx4 zero = {0.f, 0.f, 0.f, 0.f};
#pragma unroll
  for (int mi = 0; mi < 8; ++mi)
#pragma unroll
    for (int ni = 0; ni < 4; ++ni) acc[mi][ni] = zero;

  short8 af[4][2], bf[4][2];

  auto stage = [&](int kt, int cn) {
    // virtual k' in [0,1536): hi*hi (kt 0..7), lo*hi (8..15), hi*lo (16..23)
    const int a_k0 = (kt * 64) & 1023;
    const int w_k0 = (kt < 16) ? ((kt * 64) & 511) : (kt * 64 - 512);
    const short* ag = A + (size_t)(m0 + srow) * 1024 + a_k0 + scol;
    const short* wg = W + (size_t)(n0 + srow) * 1024 + w_k0 + scol;
    short* al = As + cn * 16384;
    short* bl = Bs + cn * 16384;
#pragma unroll
    for (int i = 0; i < 4; ++i) {
      const int ch = wv + i * 8;  // chunk = 8 rows; wave-uniform LDS base
      load_lds16(ag + (size_t)ch * 8192, al + ch * 512);
      load_lds16(wg + (size_t)ch * 8192, bl + ch * 512);
    }
  };

  // prologue: tile 0 -> buf 0 (landed), tile 1 -> buf 1 (in flight)
  stage(0, 0);
  stage(1, 1);
  asm volatile("s_waitcnt vmcnt(8)" ::: "memory");
  __builtin_amdgcn_s_barrier();

  for (int t = 0; t < 24; ++t) {
    const int c = t & 1;
    const short* Ab = As + c * 16384;
    const short* Bb = Bs + c * 16384;

    // ---- P0: reads for Q0 ------------------------------------------------
#pragma unroll
    for (int mi = 0; mi < 4; ++mi) {
      af[mi][0] = *(const short8*)(Ab + arow + mi * 1024 + col0);
      af[mi][1] = *(const short8*)(Ab + arow + mi * 1024 + col1);
    }
#pragma unroll
    for (int ni = 0; ni < 2; ++ni) {
      bf[ni][0] = *(const short8*)(Bb + brow + ni * 1024 + col0);
      bf[ni][1] = *(const short8*)(Bb + brow + ni * 1024 + col1);
    }
    __builtin_amdgcn_s_barrier();
    asm volatile("s_waitcnt lgkmcnt(0)" ::: "memory");
    __builtin_amdgcn_s_setprio(1);
#pragma unroll
    for (int mi = 0; mi < 4; ++mi)
#pragma unroll
      for (int ni = 0; ni < 2; ++ni) {
        acc[mi][ni] = __builtin_amdgcn_mfma_f32_16x16x32_bf16(
            af[mi][0], bf[ni][0], acc[mi][ni], 0, 0, 0);
        acc[mi][ni] = __builtin_amdgcn_mfma_f32_16x16x32_bf16(
            af[mi][1], bf[ni][1], acc[mi][ni], 0, 0, 0);
      }
    __builtin_amdgcn_s_setprio(0);
    __builtin_amdgcn_s_barrier();

    // ---- P1: reads bf[2..3]; Q1 ------------------------------------------
#pragma unroll
    for (int ni = 2; ni < 4; ++ni) {
      bf[ni][0] = *(const short8*)(Bb + brow + ni * 1024 + col0);
      bf[ni][1] = *(const short8*)(Bb + brow + ni * 1024 + col1);
    }
    __builtin_amdgcn_s_barrier();
    asm volatile("s_waitcnt lgkmcnt(0)" ::: "memory");
    __builtin_amdgcn_s_setprio(1);
#pragma unroll
    for (int mi = 0; mi < 4; ++mi)
#pragma unroll
      for (int ni = 2; ni < 4; ++ni) {
        acc[mi][ni] = __builtin_amdgcn_mfma_f32_16x16x32_bf16(
            af[mi][0], bf[ni][0], acc[mi][ni], 0, 0, 0);
        acc[mi][ni] = __builtin_amdgcn_mfma_f32_16x16x32_bf16(
            af[mi][1], bf[ni][1], acc[mi][ni], 0, 0, 0);
      }
    __builtin_amdgcn_s_setprio(0);
    __builtin_amdgcn_s_barrier();

    // ---- P2: reads af[mi4-7] (reuse regs); Q2 (reuses bf[0..1]) ----------
#pragma unroll
    for (int mi = 0; mi < 4; ++mi) {
      af[mi][0] = *(const short8*)(Ab + arow + (mi + 4) * 1024 + col0);
      af[mi][1] = *(const short8*)(Ab + arow + (mi + 4) * 1024 + col1);
    }
    __builtin_amdgcn_s_barrier();
    asm volatile("s_waitcnt lgkmcnt(0)" ::: "memory");
    __builtin_amdgcn_s_setprio(1);
#pragma unroll
    for (int mi = 0; mi < 4; ++mi)
#pragma unroll
      for (int ni = 0; ni < 2; ++ni) {
        acc[mi + 4][ni] = __builtin_amdgcn_mfma_f32_16x16x32_bf16(
            af[mi][0], bf[ni][0], acc[mi + 4][ni], 0, 0, 0);
        acc[mi + 4][ni] = __builtin_amdgcn_mfma_f32_16x16x32_bf16(
            af[mi][1], bf[ni][1], acc[mi + 4][ni], 0, 0, 0);
      }
    __builtin_amdgcn_s_setprio(0);
    __builtin_amdgcn_s_barrier();

    // ---- P3: issue tile t+2 into buf c (free since P2's barrier); Q3;
    //          counted wait (retire t+1's loads, keep t+2's in flight) ------
    if (t < 22) stage(t + 2, c);
    __builtin_amdgcn_s_setprio(1);
#pragma unroll
    for (int mi = 0; mi < 4; ++mi)
#pragma unroll
      for (int ni = 2; ni < 4; ++ni) {
        acc[mi + 4][ni] = __builtin_amdgcn_mfma_f32_16x16x32_bf16(
            af[mi][0], bf[ni][0], acc[mi + 4][ni], 0, 0, 0);
        acc[mi + 4][ni] = __builtin_amdgcn_mfma_f32_16x16x32_bf16(
            af[mi][1], bf[ni][1], acc[mi + 4][ni], 0, 0, 0);
      }
    __builtin_amdgcn_s_setprio(0);
    __builtin_amdgcn_sched_barrier(0);  // keep Q3's MFMAs above the wait
    if (t < 22) {
      asm volatile("s_waitcnt vmcnt(8)" ::: "memory");
    } else {
      asm volatile("s_waitcnt vmcnt(0)" ::: "memory");
    }
    __builtin_amdgcn_s_barrier();
  }

  // ---- epilogue: d2 -> packed per-row min --------------------------------
  __syncthreads();  // full drain before aliasing As

  float ct[4];
#pragma unroll
  for (int ni = 0; ni < 4; ++ni) {
    const int k = n0 + wn * 64 + ni * 16 + l15;
    float s = 0.f;
#pragma unroll
    for (int cc = 0; cc < 8; ++cc) s += colpart[(size_t)cc * K_CODES + k];
    ct[ni] = s;
  }

  unsigned long long* lds_min = (unsigned long long*)As;  // [256][4] = 8 KB

#pragma unroll
  for (int mi = 0; mi < 8; ++mi) {
    float rt[4];
#pragma unroll
    for (int r = 0; r < 4; ++r)
      rt[r] = row_term[m0 + wm * 128 + mi * 16 + q * 4 + r];
#pragma unroll
    for (int r = 0; r < 4; ++r) {
      unsigned long long v = ~0ull;
#pragma unroll
      for (int ni = 0; ni < 4; ++ni) {
        float d2 = rt[r] + ct[ni] - 2.0f * acc[mi][ni][r];
        d2 = fmaxf(d2, 0.0f);  // >=0 so float bit order == value order
        unsigned long long p =
            ((unsigned long long)__float_as_uint(d2) << 32) |
            (unsigned int)(n0 + wn * 64 + ni * 16 + l15);
        v = p < v ? p : v;
      }
#pragma unroll
      for (int mms = 1; mms < 16; mms <<= 1) {
        unsigned long long o = __shfl_xor(v, mms, 64);
        v = o < v ? o : v;
      }
      if (l15 == 0)
        lds_min[(wm * 128 + mi * 16 + q * 4 + r) * 4 + wn] = v;
    }
  }
  __syncthreads();
  if (tid < 256) {
    unsigned long long v0 = lds_min[tid * 4 + 0];
    unsigned long long v1 = lds_min[tid * 4 + 1];
    unsigned long long v2 = lds_min[tid * 4 + 2];
    unsigned long long v3 = lds_min[tid * 4 + 3];
    v0 = v1 < v0 ? v1 : v0;
    v2 = v3 < v2 ? v3 : v2;
    v0 = v2 < v0 ? v2 : v0;
    partial[(size_t)nt * B_ROWS + m0 + tid] = v0;
  }
}

// ---------------------------------------------------------------------------
// finalize: per-row min over 64 N-tiles (4 threads/row x 16 tiles), sqrt,
// gather locations, loss; last-arriving block writes the final mean loss.
// ---------------------------------------------------------------------------
__global__ void finalize_kernel(const unsigned long long* __restrict__ partial,
                                const float* __restrict__ loc,
                                float* __restrict__ out,
                                float* __restrict__ loss_acc,
                                unsigned int* __restrict__ counter) {
  __shared__ unsigned long long red[4][64];
  const int t = threadIdx.x;   // 256
  const int rl = t & 63;       // row-local
  const int p = t >> 6;        // partial-chunk 0..3
  const int b = blockIdx.x * 64 + rl;
  unsigned long long v = ~0ull;
#pragma unroll
  for (int i = 0; i < 16; ++i) {
    int nt = p * 16 + i;
    unsigned long long pv = partial[(size_t)nt * B_ROWS + b];
    v = pv < v ? pv : v;
  }
  red[p][rl] = v;
  __syncthreads();
  if (t < 64) {
    unsigned long long v0 = red[0][t], v1 = red[1][t];
    unsigned long long v2 = red[2][t], v3 = red[3][t];
    v0 = v1 < v0 ? v1 : v0;
    v2 = v3 < v2 ? v3 : v2;
    v0 = v2 < v0 ? v2 : v0;
    unsigned int k = (unsigned int)(v0 & 0xFFFFFFFFu);
    float d2 = __uint_as_float((unsigned int)(v0 >> 32));
    float dist = sqrtf(d2);
    int row = blockIdx.x * 64 + t;
    out[2 * row] = loc[2 * k];
    out[2 * row + 1] = loc[2 * k + 1];
    float s = dist;
#pragma unroll
    for (int m = 1; m < 64; m <<= 1) s += __shfl_xor(s, m, 64);
    if (t == 0) {
      atomicAdd(loss_acc, s);
      __threadfence();
      unsigned int old = atomicAdd(counter, 1u);
      if (old == gridDim.x - 1) {
        __threadfence();
        float total = atomicAdd(loss_acc, 0.0f);  // coherent read-back
        out[2 * B_ROWS] = total * (1.0f / (float)B_ROWS);
      }
    }
  }
}

// ---------------------------------------------------------------------------
// Workspace layout (bytes):
//   A_cat    4096*1024*2  =  8,388,608   @ 0
//   W_cat   16384*1024*2  = 33,554,432   @ 8,388,608
//   row_term  4096*4      =     16,384   @ 41,943,040
//   colpart  8*16384*4    =    524,288   @ 41,959,424
//   partial  64*4096*8    =  2,097,152   @ 42,483,712  (64 N-tiles)
//   loss_acc 4                           @ 46,678,016
//   counter  4                           @ 46,678,020
// total ~46.7 MB
// ---------------------------------------------------------------------------
extern "C" void kernel_launch(void* const* d_in, const int* in_sizes, int n_in,
                              void* d_out, int out_size, void* d_ws, size_t ws_size,
                              hipStream_t stream) {
  const float* x = (const float*)d_in[0];
  const float* w = (const float*)d_in[1];
  const float* loc = (const float*)d_in[2];
  float* out = (float*)d_out;
  char* ws = (char*)d_ws;

  short* A = (short*)(ws + 0);
  short* W = (short*)(ws + 8388608);
  float* row_term = (float*)(ws + 41943040);
  float* colpart = (float*)(ws + 41959424);
  unsigned long long* partial = (unsigned long long*)(ws + 42483712);
  float* loss_acc = (float*)(ws + 46678016);
  unsigned int* counter = (unsigned int*)(ws + 46678020);

  prep_kernel<<<2304, 256, 0, stream>>>(x, w, A, W, row_term, colpart,
                                        loss_acc, counter);
  som_gemm_kernel<<<1024, 512, 0, stream>>>(A, W, row_term, colpart, partial);
  finalize_kernel<<<B_ROWS / 64, 256, 0, stream>>>(partial, loc, out, loss_acc,
                                                   counter);
}

// Round 3
// 299.904 us; speedup vs baseline: 1.0153x; 1.0153x over previous
//
#include <hip/hip_runtime.h>
#include <stdint.h>

// Problem constants (fixed by reference setup_inputs)
#define B_ROWS 4096
#define D_DIM  512
#define K_CODES 16384
#define EPS 1e-6f

typedef __attribute__((ext_vector_type(8))) short short8;   // 8 bf16 (raw bits)
typedef __attribute__((ext_vector_type(4))) float floatx4;  // MFMA accumulator

__device__ __forceinline__ unsigned short f2bf(float f) {
  // round-to-nearest-even fp32 -> bf16 (inputs finite, no NaN handling)
  unsigned int u = __float_as_uint(f);
  u += 0x7FFFu + ((u >> 16) & 1u);
  return (unsigned short)(u >> 16);
}
__device__ __forceinline__ float bf2f(unsigned short h) {
  return __uint_as_float(((unsigned int)h) << 16);
}

__device__ __forceinline__ void load_lds16(const short* g, short* l) {
  // async global->LDS, 16B/lane; LDS dest = wave-uniform base + lane*16
  __builtin_amdgcn_global_load_lds(
      (const __attribute__((address_space(1))) void*)g,
      (__attribute__((address_space(3))) void*)l, 16, 0, 0);
}

// ---------------------------------------------------------------------------
// prep (single launch; unchanged):
//  blocks 0..2047  : w-tile path. w (512x16384 f32) -> W_cat (16384x1024 bf16
//                    [w_hi|w_lo], K-major) via 64x64 LDS transpose (+1 pad),
//                    float4 reads, short8 (16B) stores. Also writes per-chunk
//                    colpart[c][k] = sum_d(w^2) - 2*eps*sum_d(w) (8 d-chunks;
//                    summed by the gemm epilogue -- no atomics, deterministic).
//  blocks 2048..2303: x path. x (4096x512) -> A_cat (4096x1024 [x_hi|x_lo]) +
//                    row_term[b] = sum(x^2)+2*eps*sum(x)+D*eps^2. One wave per
//                    row, 16 rows/block. Block 2048 inits loss/counter.
// ---------------------------------------------------------------------------
__global__ void prep_kernel(const float* __restrict__ x,
                            const float* __restrict__ w,
                            short* __restrict__ A, short* __restrict__ W,
                            float* __restrict__ row_term,
                            float* __restrict__ colpart,
                            float* __restrict__ loss_acc,
                            unsigned int* __restrict__ counter) {
  const int bid = blockIdx.x;
  const int t = threadIdx.x;  // 256
  if (bid < 2048) {
    __shared__ float tile[64][65];
    const int k0 = (bid & 255) * 64;
    const int dchunk = bid >> 8;  // 0..7
    const int d0 = dchunk * 64;
#pragma unroll
    for (int i = 0; i < 4; ++i) {
      int idx = i * 256 + t;
      int r = idx >> 4, c4 = (idx & 15) * 4;  // r: d-local
      float4 v = *(const float4*)&w[(size_t)(d0 + r) * K_CODES + k0 + c4];
      tile[r][c4 + 0] = v.x;
      tile[r][c4 + 1] = v.y;
      tile[r][c4 + 2] = v.z;
      tile[r][c4 + 3] = v.w;
    }
    __syncthreads();
    const int sub = t & 7;    // d-subgroup within a k row
    const int cd8 = sub * 8;  // 8 consecutive d
#pragma unroll
    for (int g = 0; g < 2; ++g) {
      const int rk = (t >> 3) + g * 32;  // k-local 0..63
      short8 hi, lo;
      float s = 0.f, q = 0.f;
#pragma unroll
      for (int j = 0; j < 8; ++j) {
        float v = tile[cd8 + j][rk];
        s += v;
        q += v * v;
        unsigned short h = f2bf(v);
        float r2 = v - bf2f(h);
        hi[j] = (short)h;
        lo[j] = (short)f2bf(r2);
      }
      *(short8*)(W + (size_t)(k0 + rk) * 1024 + d0 + cd8) = hi;
      *(short8*)(W + (size_t)(k0 + rk) * 1024 + 512 + d0 + cd8) = lo;
#pragma unroll
      for (int m = 1; m < 8; m <<= 1) {
        s += __shfl_xor(s, m, 64);
        q += __shfl_xor(q, m, 64);
      }
      if (sub == 0)
        colpart[(size_t)dchunk * K_CODES + k0 + rk] = q - 2.0f * EPS * s;
    }
  } else {
    const int xb = bid - 2048;  // 0..255
    if (xb == 0 && t == 0) { loss_acc[0] = 0.0f; counter[0] = 0u; }
    const int wv = t >> 6, lane = t & 63;
#pragma unroll
    for (int i = 0; i < 4; ++i) {
      const int b = xb * 16 + i * 4 + wv;  // one wave per row
      const float* xr = x + (size_t)b * D_DIM;
      float4 v0 = ((const float4*)xr)[lane * 2];
      float4 v1 = ((const float4*)xr)[lane * 2 + 1];
      float vals[8] = {v0.x, v0.y, v0.z, v0.w, v1.x, v1.y, v1.z, v1.w};
      short8 hi, lo;
      float s = 0.f, q = 0.f;
#pragma unroll
      for (int j = 0; j < 8; ++j) {
        float v = vals[j];
        s += v;
        q += v * v;
        unsigned short h = f2bf(v);
        float r = v - bf2f(h);
        hi[j] = (short)h;
        lo[j] = (short)f2bf(r);
      }
      *(short8*)(A + (size_t)b * 1024 + lane * 8) = hi;
      *(short8*)(A + (size_t)b * 1024 + 512 + lane * 8) = lo;
#pragma unroll
      for (int m = 1; m < 64; m <<= 1) {
        s += __shfl_xor(s, m, 64);
        q += __shfl_xor(q, m, 64);
      }
      if (lane == 0) row_term[b] = q + 2.0f * EPS * s + (float)D_DIM * EPS * EPS;
    }
  }
}

// ---------------------------------------------------------------------------
// som_gemm (R7): persistent 256 blocks (1/CU), each runs 4 (mt,nt) work items
// with nt CONSTANT per block (W panel L2-hot) and a flattened 96-tile pipeline
// that never drains across item boundaries.
//   item mapping: xcd=bid&7, w=bid>>3; nt = xcd*8 + (w&7); mt = (w>>3) + 4*it.
// Per K-tile (4 phases), FINE-GRAINED staging (m196: coarse split = -7..27%):
//   P0: ds_read af[0-3]+bf[0-1] (12xb128); stage A1(g+1) (2 loads); bar;
//       lgkm0; prio1; 16 MFMA; prio0; bar
//   P1: ds_read bf[2-3] (4);  stage B0(g+1); bar; lgkm0; 16 MFMA; bar
//   P2: ds_read af[4-7] (8);  stage B1(g+1); bar; lgkm0; 16 MFMA; bar
//       [after P2's barrier buf c has no more readers this tile]
//   P3: stage A0(g+2) -> buf c (legal post-P2-bar); 16 MFMA; sched_barrier;
//       s_waitcnt vmcnt(2)  <- retires the 8 loads of tile g+1 (issued over
//       the previous 4 phases, >=1 phase of MFMA cover each), keeps A0(g+2)
//       in flight; NEVER 0 mid-loop. Tail (g>=94): vmcnt(0).
// Epilogue at kt==23 runs while tile g+1 (next item's tile 0) is already
// landed and A0(g+2) is in flight -> no pass-boundary pipeline drain.
// lds_min is its own 8KB buffer (LDS 136KB total, still 1 block/CU); ct[]
// (colpart sums, nt-only) hoisted out of the loop.
// MFMA accumulation order per acc element identical to R5/R6 (kt asc, ks asc,
// acc reset per item) -> bitwise-identical d2 -> absmax stays 0.
// ---------------------------------------------------------------------------
__global__ __launch_bounds__(512, 2) void som_gemm_kernel(
    const short* __restrict__ A, const short* __restrict__ W,
    const float* __restrict__ row_term, const float* __restrict__ colpart,
    unsigned long long* __restrict__ partial) {
  __shared__ __align__(16) short As[2 * 16384];  // 2 x 256x64 bf16 = 64 KB
  __shared__ __align__(16) short Bs[2 * 16384];  // 64 KB
  __shared__ unsigned long long lds_min[256 * 4];  // 8 KB (epilogue scratch)

  const int bid = blockIdx.x;           // 0..255, persistent
  const int xcd = bid & 7;
  const int w_ = bid >> 3;              // 0..31 within XCD panel
  const int nt = xcd * 8 + (w_ & 7);    // constant per block
  const int mt_base = w_ >> 3;          // 0..3; mt = mt_base + 4*it
  const int n0 = nt * 256;

  const int tid = threadIdx.x;          // 512
  const int wv = tid >> 6, lane = tid & 63;
  const int wm = wv >> 2, wn = wv & 3;  // wave -> 128x64 output sub-tile
  const int q = lane >> 4, l15 = lane & 15;

  // staging address pieces (pre-swizzled global source, linear LDS dest)
  const int srow = lane >> 3;
  const int scol = ((lane & 7) ^ (srow & 7)) * 8;

  // fragment-read address pieces (row&7 == l15&7 since offsets are mult of 8)
  const int arow = (wm * 128 + l15) * 64;  // + mi*1024
  const int brow = (wn * 64 + l15) * 64;   // + ni*1024
  const int col0 = ((0 + q) ^ (l15 & 7)) * 8;  // ks=0 swizzled col
  const int col1 = ((4 + q) ^ (l15 & 7)) * 8;  // ks=1 swizzled col

  // ct depends only on nt -> hoist (loads retire before the pipeline fills)
  float ct[4];
#pragma unroll
  for (int ni = 0; ni < 4; ++ni) {
    const int k = n0 + wn * 64 + ni * 16 + l15;
    float s = 0.f;
#pragma unroll
    for (int cc = 0; cc < 8; ++cc) s += colpart[(size_t)cc * K_CODES + k];
    ct[ni] = s;
  }

  floatx4 acc[8][4];
  const floatx4 zero = {0.f, 0.f, 0.f, 0.f};
#pragma unroll
  for (int mi = 0; mi < 8; ++mi)
#pragma unroll
    for (int ni = 0; ni < 4; ++ni) acc[mi][ni] = zero;

  short8 af[4][2], bf[4][2];

  // stage one 16KB half-tile (2 loads/thread) of global tile g.
  // h: 0=A rows 0-127, 1=A rows 128-255, 2=B rows 0-127, 3=B rows 128-255
  auto stage_half = [&](int g, int h) {
    const int it = g / 24, kt = g - it * 24;
    // virtual k' in [0,1536): hi*hi (kt 0..7), lo*hi (8..15), hi*lo (16..23)
    const int a_k0 = (kt * 64) & 1023;
    const int w_k0 = (kt < 16) ? ((kt * 64) & 511) : (kt * 64 - 512);
    const int cn = g & 1;
    if (h < 2) {
      const int m0g = (mt_base + 4 * it) * 256;
      const short* ag = A + (size_t)(m0g + srow) * 1024 + a_k0 + scol;
      short* al = As + cn * 16384;
      const int c0 = wv + h * 16;  // chunks {c0, c0+8} = this wave's 2 chunks
      load_lds16(ag + (size_t)c0 * 8192, al + c0 * 512);
      load_lds16(ag + (size_t)(c0 + 8) * 8192, al + (c0 + 8) * 512);
    } else {
      const short* wg = W + (size_t)(n0 + srow) * 1024 + w_k0 + scol;
      short* bl = Bs + cn * 16384;
      const int c0 = wv + (h - 2) * 16;
      load_lds16(wg + (size_t)c0 * 8192, bl + c0 * 512);
      load_lds16(wg + (size_t)(c0 + 8) * 8192, bl + (c0 + 8) * 512);
    }
  };

  // prologue: tile 0 fully staged + A0 of tile 1 in flight (steady pattern)
  stage_half(0, 0);
  stage_half(0, 1);
  stage_half(0, 2);
  stage_half(0, 3);
  stage_half(1, 0);
  asm volatile("s_waitcnt vmcnt(2)" ::: "memory");
  __builtin_amdgcn_s_barrier();

  for (int g = 0; g < 96; ++g) {
    const int it = g / 24;
    const int kt = g - it * 24;
    const int c = g & 1;
    const short* Ab = As + c * 16384;
    const short* Bb = Bs + c * 16384;

    // ---- P0: reads for Q0; stage A1(g+1) ---------------------------------
#pragma unroll
    for (int mi = 0; mi < 4; ++mi) {
      af[mi][0] = *(const short8*)(Ab + arow + mi * 1024 + col0);
      af[mi][1] = *(const short8*)(Ab + arow + mi * 1024 + col1);
    }
#pragma unroll
    for (int ni = 0; ni < 2; ++ni) {
      bf[ni][0] = *(const short8*)(Bb + brow + ni * 1024 + col0);
      bf[ni][1] = *(const short8*)(Bb + brow + ni * 1024 + col1);
    }
    if (g + 1 < 96) stage_half(g + 1, 1);
    __builtin_amdgcn_s_barrier();
    asm volatile("s_waitcnt lgkmcnt(0)" ::: "memory");
    __builtin_amdgcn_s_setprio(1);
#pragma unroll
    for (int mi = 0; mi < 4; ++mi)
#pragma unroll
      for (int ni = 0; ni < 2; ++ni) {
        acc[mi][ni] = __builtin_amdgcn_mfma_f32_16x16x32_bf16(
            af[mi][0], bf[ni][0], acc[mi][ni], 0, 0, 0);
        acc[mi][ni] = __builtin_amdgcn_mfma_f32_16x16x32_bf16(
            af[mi][1], bf[ni][1], acc[mi][ni], 0, 0, 0);
      }
    __builtin_amdgcn_s_setprio(0);
    __builtin_amdgcn_s_barrier();

    // ---- P1: reads bf[2..3]; stage B0(g+1); Q1 ---------------------------
#pragma unroll
    for (int ni = 2; ni < 4; ++ni) {
      bf[ni][0] = *(const short8*)(Bb + brow + ni * 1024 + col0);
      bf[ni][1] = *(const short8*)(Bb + brow + ni * 1024 + col1);
    }
    if (g + 1 < 96) stage_half(g + 1, 2);
    __builtin_amdgcn_s_barrier();
    asm volatile("s_waitcnt lgkmcnt(0)" ::: "memory");
    __builtin_amdgcn_s_setprio(1);
#pragma unroll
    for (int mi = 0; mi < 4; ++mi)
#pragma unroll
      for (int ni = 2; ni < 4; ++ni) {
        acc[mi][ni] = __builtin_amdgcn_mfma_f32_16x16x32_bf16(
            af[mi][0], bf[ni][0], acc[mi][ni], 0, 0, 0);
        acc[mi][ni] = __builtin_amdgcn_mfma_f32_16x16x32_bf16(
            af[mi][1], bf[ni][1], acc[mi][ni], 0, 0, 0);
      }
    __builtin_amdgcn_s_setprio(0);
    __builtin_amdgcn_s_barrier();

    // ---- P2: reads af[4-7] (reuse regs); stage B1(g+1); Q2 ---------------
#pragma unroll
    for (int mi = 0; mi < 4; ++mi) {
      af[mi][0] = *(const short8*)(Ab + arow + (mi + 4) * 1024 + col0);
      af[mi][1] = *(const short8*)(Ab + arow + (mi + 4) * 1024 + col1);
    }
    if (g + 1 < 96) stage_half(g + 1, 3);
    __builtin_amdgcn_s_barrier();
    asm volatile("s_waitcnt lgkmcnt(0)" ::: "memory");
    __builtin_amdgcn_s_setprio(1);
#pragma unroll
    for (int mi = 0; mi < 4; ++mi)
#pragma unroll
      for (int ni = 0; ni < 2; ++ni) {
        acc[mi + 4][ni] = __builtin_amdgcn_mfma_f32_16x16x32_bf16(
            af[mi][0], bf[ni][0], acc[mi + 4][ni], 0, 0, 0);
        acc[mi + 4][ni] = __builtin_amdgcn_mfma_f32_16x16x32_bf16(
            af[mi][1], bf[ni][1], acc[mi + 4][ni], 0, 0, 0);
      }
    __builtin_amdgcn_s_setprio(0);
    __builtin_amdgcn_s_barrier();

    // ---- P3: stage A0(g+2) into buf c (free post-P2-bar); Q3; vmcnt(2) ---
    if (g + 2 < 96) stage_half(g + 2, 0);
    __builtin_amdgcn_s_setprio(1);
#pragma unroll
    for (int mi = 0; mi < 4; ++mi)
#pragma unroll
      for (int ni = 2; ni < 4; ++ni) {
        acc[mi + 4][ni] = __builtin_amdgcn_mfma_f32_16x16x32_bf16(
            af[mi][0], bf[ni][0], acc[mi + 4][ni], 0, 0, 0);
        acc[mi + 4][ni] = __builtin_amdgcn_mfma_f32_16x16x32_bf16(
            af[mi][1], bf[ni][1], acc[mi + 4][ni], 0, 0, 0);
      }
    __builtin_amdgcn_s_setprio(0);
    __builtin_amdgcn_sched_barrier(0);  // keep Q3's MFMAs above the wait
    if (g + 2 < 96) {
      asm volatile("s_waitcnt vmcnt(2)" ::: "memory");
    } else {
      asm volatile("s_waitcnt vmcnt(0)" ::: "memory");
    }
    __builtin_amdgcn_s_barrier();

    // ---- item epilogue (pipeline for next item already in flight) --------
    if (kt == 23) {
      const int m0e = (mt_base + 4 * it) * 256;
#pragma unroll
      for (int mi = 0; mi < 8; ++mi) {
        float rt[4];
#pragma unroll
        for (int r = 0; r < 4; ++r)
          rt[r] = row_term[m0e + wm * 128 + mi * 16 + q * 4 + r];
#pragma unroll
        for (int r = 0; r < 4; ++r) {
          unsigned long long v = ~0ull;
#pragma unroll
          for (int ni = 0; ni < 4; ++ni) {
            float d2 = rt[r] + ct[ni] - 2.0f * acc[mi][ni][r];
            d2 = fmaxf(d2, 0.0f);  // >=0 so float bit order == value order
            unsigned long long p =
                ((unsigned long long)__float_as_uint(d2) << 32) |
                (unsigned int)(n0 + wn * 64 + ni * 16 + l15);
            v = p < v ? p : v;
          }
#pragma unroll
          for (int mms = 1; mms < 16; mms <<= 1) {
            unsigned long long o = __shfl_xor(v, mms, 64);
            v = o < v ? o : v;
          }
          if (l15 == 0)
            lds_min[(wm * 128 + mi * 16 + q * 4 + r) * 4 + wn] = v;
        }
      }
      asm volatile("s_waitcnt lgkmcnt(0)" ::: "memory");
      __builtin_amdgcn_s_barrier();
      if (tid < 256) {
        unsigned long long v0 = lds_min[tid * 4 + 0];
        unsigned long long v1 = lds_min[tid * 4 + 1];
        unsigned long long v2 = lds_min[tid * 4 + 2];
        unsigned long long v3 = lds_min[tid * 4 + 3];
        v0 = v1 < v0 ? v1 : v0;
        v2 = v3 < v2 ? v3 : v2;
        v0 = v2 < v0 ? v2 : v0;
        partial[(size_t)nt * B_ROWS + m0e + tid] = v0;
      }
      if (it < 3) {
#pragma unroll
        for (int mi = 0; mi < 8; ++mi)
#pragma unroll
          for (int ni = 0; ni < 4; ++ni) acc[mi][ni] = zero;
      }
    }
  }
}

// ---------------------------------------------------------------------------
// finalize: per-row min over 64 N-tiles (4 threads/row x 16 tiles), sqrt,
// gather locations, loss; last-arriving block writes the final mean loss.
// ---------------------------------------------------------------------------
__global__ void finalize_kernel(const unsigned long long* __restrict__ partial,
                                const float* __restrict__ loc,
                                float* __restrict__ out,
                                float* __restrict__ loss_acc,
                                unsigned int* __restrict__ counter) {
  __shared__ unsigned long long red[4][64];
  const int t = threadIdx.x;   // 256
  const int rl = t & 63;       // row-local
  const int p = t >> 6;        // partial-chunk 0..3
  const int b = blockIdx.x * 64 + rl;
  unsigned long long v = ~0ull;
#pragma unroll
  for (int i = 0; i < 16; ++i) {
    int nt = p * 16 + i;
    unsigned long long pv = partial[(size_t)nt * B_ROWS + b];
    v = pv < v ? pv : v;
  }
  red[p][rl] = v;
  __syncthreads();
  if (t < 64) {
    unsigned long long v0 = red[0][t], v1 = red[1][t];
    unsigned long long v2 = red[2][t], v3 = red[3][t];
    v0 = v1 < v0 ? v1 : v0;
    v2 = v3 < v2 ? v3 : v2;
    v0 = v2 < v0 ? v2 : v0;
    unsigned int k = (unsigned int)(v0 & 0xFFFFFFFFu);
    float d2 = __uint_as_float((unsigned int)(v0 >> 32));
    float dist = sqrtf(d2);
    int row = blockIdx.x * 64 + t;
    out[2 * row] = loc[2 * k];
    out[2 * row + 1] = loc[2 * k + 1];
    float s = dist;
#pragma unroll
    for (int m = 1; m < 64; m <<= 1) s += __shfl_xor(s, m, 64);
    if (t == 0) {
      atomicAdd(loss_acc, s);
      __threadfence();
      unsigned int old = atomicAdd(counter, 1u);
      if (old == gridDim.x - 1) {
        __threadfence();
        float total = atomicAdd(loss_acc, 0.0f);  // coherent read-back
        out[2 * B_ROWS] = total * (1.0f / (float)B_ROWS);
      }
    }
  }
}

// ---------------------------------------------------------------------------
// Workspace layout (bytes):
//   A_cat    4096*1024*2  =  8,388,608   @ 0
//   W_cat   16384*1024*2  = 33,554,432   @ 8,388,608
//   row_term  4096*4      =     16,384   @ 41,943,040
//   colpart  8*16384*4    =    524,288   @ 41,959,424
//   partial  64*4096*8    =  2,097,152   @ 42,483,712  (64 N-tiles)
//   loss_acc 4                           @ 46,678,016
//   counter  4                           @ 46,678,020
// total ~46.7 MB
// ---------------------------------------------------------------------------
extern "C" void kernel_launch(void* const* d_in, const int* in_sizes, int n_in,
                              void* d_out, int out_size, void* d_ws, size_t ws_size,
                              hipStream_t stream) {
  const float* x = (const float*)d_in[0];
  const float* w = (const float*)d_in[1];
  const float* loc = (const float*)d_in[2];
  float* out = (float*)d_out;
  char* ws = (char*)d_ws;

  short* A = (short*)(ws + 0);
  short* W = (short*)(ws + 8388608);
  float* row_term = (float*)(ws + 41943040);
  float* colpart = (float*)(ws + 41959424);
  unsigned long long* partial = (unsigned long long*)(ws + 42483712);
  float* loss_acc = (float*)(ws + 46678016);
  unsigned int* counter = (unsigned int*)(ws + 46678020);

  prep_kernel<<<2304, 256, 0, stream>>>(x, w, A, W, row_term, colpart,
                                        loss_acc, counter);
  som_gemm_kernel<<<256, 512, 0, stream>>>(A, W, row_term, colpart, partial);
  finalize_kernel<<<B_ROWS / 64, 256, 0, stream>>>(partial, loc, out, loss_acc,
                                                   counter);
}